// Round 1
// baseline (102.514 us; speedup 1.0000x reference)
//
#include <hip/hip_runtime.h>
#include <math.h>
#include <stdint.h>

#define THRES 0.12f
#define MAXDETS 3
#define RES 7
#define NCELL (RES * RES)

// key = (score_bits << 32) | (0xFFFFFFFF - idx)
// monotone: higher score => larger key; equal score => smaller idx => larger key.
// Scores are either > 0.12 (positive floats: bit pattern order-preserving) or -inf
// (sign bit set -> negative int32 -> below every positive), so int64 compare works.
__device__ __forceinline__ long long make_key(float s, int idx) {
    int sb = __float_as_int(s);
    unsigned int low = 0xFFFFFFFFu - (unsigned int)idx;
    return ((long long)sb << 32) | (long long)low;
}

__global__ __launch_bounds__(256)
void frcnn_post(const float* __restrict__ boxes,   // [B,N,4]
                const int* __restrict__ labels,    // [B,N]
                const float* __restrict__ scores,  // [B,N]
                const int* __restrict__ Hp,
                const int* __restrict__ Wp,
                float* __restrict__ out,           // classes [B*3*49] ++ boxes [B*15*49]
                int B, int N)
{
    extern __shared__ float2 sdata[];  // N entries: {masked_score, bin_as_int_bits}
    const int b = blockIdx.x;
    const int tid = threadIdx.x;
    const int lane = tid & 63;
    const int wave = tid >> 6;
    const int nwaves = blockDim.x >> 6;

    const float Hf = (float)Hp[0];
    // reference: ar = W/H in python double, then used as a weak scalar in fp32 ops
    const float ar = (float)((double)Wp[0] / (double)Hp[0]);

    const float* bb = boxes + (size_t)b * N * 4;
    const float* ss = scores + (size_t)b * N;

    // ---- Phase 1: per-box bin + masked score into LDS ----
    for (int n = tid; n < N; n += blockDim.x) {
        float4 v = ((const float4*)bb)[n];
        float s = ss[n];
        float nb0 = v.x / Hf, nb1 = v.y / Hf, nb2 = v.z / Hf, nb3 = v.w / Hf;
        float cx = (nb0 + nb2) * 0.5f;
        float cy = (nb1 + nb3) * 0.5f;
        int px = 0, py = 0;
#pragma unroll
        for (int j = 1; j < RES; ++j) {
            float bj = (float)j / (float)RES;   // bins = arange(1,7)/7 in fp32
            px += (cx >= ar * bj) ? 1 : 0;      // digitize, right=False
            py += (cy >= bj) ? 1 : 0;
        }
        int bin = py * RES + px;
        float ms = (s > THRES) ? s : -INFINITY;  // kept mask
        sdata[n] = make_float2(ms, __int_as_float(bin));
    }
    __syncthreads();

    const long long SENT = ((long long)(int)0xFF800000) << 32;  // score = -inf

    // ---- Phase 2: per-cell top-3 (one wave per cell, round-robin) ----
    for (int cell = wave; cell < NCELL; cell += nwaves) {
        long long k0 = SENT, k1 = SENT, k2 = SENT;
        for (int n = lane; n < N; n += 64) {
            float2 e = sdata[n];
            int bin = __float_as_int(e.y);
            if (bin == cell && e.x > THRES) {
                long long k = make_key(e.x, n);
                if (k > k0)      { k2 = k1; k1 = k0; k0 = k; }
                else if (k > k1) { k2 = k1; k1 = k; }
                else if (k > k2) { k2 = k; }
            }
        }
        // butterfly merge of sorted triples across 64 lanes
#pragma unroll
        for (int m = 1; m < 64; m <<= 1) {
            long long o0 = __shfl_xor(k0, m, 64);
            long long o1 = __shfl_xor(k1, m, 64);
            long long o2 = __shfl_xor(k2, m, 64);
            bool t0 = k0 >= o0;
            long long r0  = t0 ? k0 : o0;
            long long nx0 = t0 ? k1 : k0;
            long long nx1 = t0 ? k2 : k1;
            long long ny0 = t0 ? o0 : o1;
            long long ny1 = t0 ? o1 : o2;
            bool t1 = nx0 >= ny0;
            long long r1 = t1 ? nx0 : ny0;
            long long mx = t1 ? nx1 : nx0;
            long long my = t1 ? ny0 : ny1;
            long long r2 = (mx >= my) ? mx : my;
            k0 = r0; k1 = r1; k2 = r2;
        }
        // lanes 0..2 emit detection k = lane
        if (lane < MAXDETS) {
            long long k = (lane == 0) ? k0 : (lane == 1) ? k1 : k2;
            float s = __int_as_float((int)(k >> 32));
            bool valid = (s > THRES);  // masked entries are exactly -inf
            float f0 = -1.0f, f1 = -1.0f, f2 = -1.0f, f3 = -1.0f, f4 = -1.0f;
            int cls = 0;
            if (valid) {
                unsigned int low = (unsigned int)(k & 0xFFFFFFFFLL);
                int idx = (int)(0xFFFFFFFFu - low);
                float4 v = ((const float4*)bb)[idx];
                float nb0 = v.x / Hf, nb1 = v.y / Hf, nb2 = v.z / Hf, nb3 = v.w / Hf;
                f0 = s;
                f1 = (nb2 - nb0) / ar;
                f2 = nb3 - nb1;
                f3 = nb0 / ar;
                f4 = nb1;
                cls = labels[(size_t)b * N + idx];
            }
            // classes_out[b, k, cell]
            out[(size_t)b * (MAXDETS * NCELL) + lane * NCELL + cell] = (float)cls;
            // boxes_out[b, k*5 + f, cell]
            float* ob = out + (size_t)B * (MAXDETS * NCELL)
                            + (size_t)b * (MAXDETS * 5 * NCELL)
                            + (lane * 5) * NCELL + cell;
            ob[0 * NCELL] = f0;
            ob[1 * NCELL] = f1;
            ob[2 * NCELL] = f2;
            ob[3 * NCELL] = f3;
            ob[4 * NCELL] = f4;
        }
    }
}

extern "C" void kernel_launch(void* const* d_in, const int* in_sizes, int n_in,
                              void* d_out, int out_size, void* d_ws, size_t ws_size,
                              hipStream_t stream) {
    const float* boxes  = (const float*)d_in[0];
    const int*   labels = (const int*)d_in[1];
    const float* scores = (const float*)d_in[2];
    const int*   Hp     = (const int*)d_in[3];
    const int*   Wp     = (const int*)d_in[4];
    float* out = (float*)d_out;

    // out = B*3*49 (classes) + B*15*49 (boxes) = B*882
    int B = out_size / (NCELL * (MAXDETS + MAXDETS * 5));
    int N = in_sizes[2] / B;   // pred_scores is [B,N]

    size_t shmem = (size_t)N * sizeof(float2);
    frcnn_post<<<B, 256, shmem, stream>>>(boxes, labels, scores, Hp, Wp, out, B, N);
}

// Round 2
// 64.932 us; speedup vs baseline: 1.5788x; 1.5788x over previous
//
#include <hip/hip_runtime.h>
#include <math.h>
#include <stdint.h>

#define THRES 0.12f
#define MAXDETS 3
#define RES 7
#define NCELL (RES * RES)
#define NSLOT (NCELL * MAXDETS)

// key = (score_bits << 32) | (0xFFFFFFFF - idx), sentinel = 0 (empty).
// All kept scores are > 0.12 > 0 -> positive fp32 bit patterns are
// order-preserving as unsigned ints; smaller idx -> larger low word,
// matching top_k's index-ascending tie-break.
__global__ __launch_bounds__(512)
void frcnn_post(const float* __restrict__ boxes,   // [B,N,4]
                const int* __restrict__ labels,    // [B,N]
                const float* __restrict__ scores,  // [B,N]
                const int* __restrict__ Hp,
                const int* __restrict__ Wp,
                float* __restrict__ out,           // classes [B*3*49] ++ boxes [B*15*49]
                int B, int N)
{
    __shared__ unsigned long long slots[NSLOT];  // [cell][k], sorted desc by cascade
    const int b = blockIdx.x;
    const int tid = threadIdx.x;

    const float Hf = (float)Hp[0];
    const float ar = (float)((double)Wp[0] / (double)Hp[0]);

    const float* bb = boxes + (size_t)b * N * 4;
    const float* ss = scores + (size_t)b * N;

    // init slots to sentinel
    for (int i = tid; i < NSLOT; i += blockDim.x) slots[i] = 0ULL;
    __syncthreads();

    // ---- Phase 1: one pass over boxes, atomic cascade top-3 insert ----
    for (int n = tid; n < N; n += blockDim.x) {
        float s = ss[n];
        if (s > THRES) {
            float4 v = ((const float4*)bb)[n];
            float nb0 = v.x / Hf, nb1 = v.y / Hf, nb2 = v.z / Hf, nb3 = v.w / Hf;
            float cx = (nb0 + nb2) * 0.5f;
            float cy = (nb1 + nb3) * 0.5f;
            int px = 0, py = 0;
#pragma unroll
            for (int j = 1; j < RES; ++j) {
                float bj = (float)j / (float)RES;   // bins = arange(1,7)/7 in fp32
                px += (cx >= ar * bj) ? 1 : 0;      // digitize, right=False
                py += (cy >= bj) ? 1 : 0;
            }
            int bin = py * RES + px;
            unsigned long long cur =
                ((unsigned long long)(unsigned int)__float_as_int(s) << 32)
                | (unsigned long long)(0xFFFFFFFFu - (unsigned int)n);
            unsigned long long* sl = &slots[bin * MAXDETS];
#pragma unroll
            for (int k = 0; k < MAXDETS; ++k) {
                unsigned long long old = atomicMax(&sl[k], cur);
                cur = (old < cur) ? old : cur;  // loser carries forward
                if (cur == 0ULL) break;
            }
        }
    }
    __syncthreads();

    // ---- Phase 2: 147 threads emit (cell, k) results ----
    if (tid < NSLOT) {
        const int k = tid / NCELL;      // det slot 0..2
        const int cell = tid % NCELL;   // 0..48
        unsigned long long key = slots[cell * MAXDETS + k];
        float f0 = -1.0f, f1 = -1.0f, f2 = -1.0f, f3 = -1.0f, f4 = -1.0f;
        int cls = 0;
        if (key != 0ULL) {
            float s = __int_as_float((int)(key >> 32));
            int idx = (int)(0xFFFFFFFFu - (unsigned int)(key & 0xFFFFFFFFULL));
            float4 v = ((const float4*)bb)[idx];
            float nb0 = v.x / Hf, nb1 = v.y / Hf, nb2 = v.z / Hf, nb3 = v.w / Hf;
            f0 = s;
            f1 = (nb2 - nb0) / ar;
            f2 = nb3 - nb1;
            f3 = nb0 / ar;
            f4 = nb1;
            cls = labels[(size_t)b * N + idx];
        }
        // classes_out[b, k, cell] — threads 0..146 write contiguously
        out[(size_t)b * NSLOT + k * NCELL + cell] = (float)cls;
        // boxes_out[b, k*5 + f, cell]
        float* ob = out + (size_t)B * NSLOT
                        + (size_t)b * (MAXDETS * 5 * NCELL)
                        + (k * 5) * NCELL + cell;
        ob[0 * NCELL] = f0;
        ob[1 * NCELL] = f1;
        ob[2 * NCELL] = f2;
        ob[3 * NCELL] = f3;
        ob[4 * NCELL] = f4;
    }
}

extern "C" void kernel_launch(void* const* d_in, const int* in_sizes, int n_in,
                              void* d_out, int out_size, void* d_ws, size_t ws_size,
                              hipStream_t stream) {
    const float* boxes  = (const float*)d_in[0];
    const int*   labels = (const int*)d_in[1];
    const float* scores = (const float*)d_in[2];
    const int*   Hp     = (const int*)d_in[3];
    const int*   Wp     = (const int*)d_in[4];
    float* out = (float*)d_out;

    int B = out_size / (NCELL * (MAXDETS + MAXDETS * 5));  // 882 per batch
    int N = in_sizes[2] / B;   // pred_scores is [B,N]

    frcnn_post<<<B, 512, 0, stream>>>(boxes, labels, scores, Hp, Wp, out, B, N);
}

// Round 3
// 63.770 us; speedup vs baseline: 1.6076x; 1.0182x over previous
//
#include <hip/hip_runtime.h>
#include <math.h>
#include <stdint.h>

#define THRES 0.12f
#define MAXDETS 3
#define RES 7
#define NCELL (RES * RES)
#define NSLOT (NCELL * MAXDETS)

// key = (score_bits << 32) | (0xFFFFFFFF - idx), sentinel = 0 (empty).
// All kept scores are > 0.12 > 0 -> positive fp32 bit patterns are
// order-preserving as unsigned ints; smaller idx -> larger low word,
// matching top_k's index-ascending tie-break.
__global__ __launch_bounds__(1024)
void frcnn_post(const float* __restrict__ boxes,   // [B,N,4]
                const int* __restrict__ labels,    // [B,N]
                const float* __restrict__ scores,  // [B,N]
                const int* __restrict__ Hp,
                const int* __restrict__ Wp,
                float* __restrict__ out,           // classes [B*3*49] ++ boxes [B*15*49]
                int B, int N)
{
    __shared__ unsigned long long slots[NSLOT];  // [cell][k], sorted desc by cascade
    extern __shared__ char smem[];
    float4* snb = (float4*)smem;                 // normalized boxes [N]
    int* slab = (int*)(smem + (size_t)N * sizeof(float4));  // labels [N]

    const int b = blockIdx.x;
    const int tid = threadIdx.x;

    const float Hf = (float)Hp[0];
    const float ar = (float)((double)Wp[0] / (double)Hp[0]);

    const float* bb = boxes + (size_t)b * N * 4;
    const float* ss = scores + (size_t)b * N;
    const int*   ll = labels + (size_t)b * N;

    // init slots to sentinel
    if (tid < NSLOT) slots[tid] = 0ULL;
    __syncthreads();

    // ---- Phase 1: one pass; all three loads independent (parallel issue) ----
    for (int n = tid; n < N; n += blockDim.x) {
        float s = ss[n];                       // independent load 1
        float4 v = ((const float4*)bb)[n];     // independent load 2 (unconditional)
        int lab = ll[n];                       // independent load 3
        float nb0 = v.x / Hf, nb1 = v.y / Hf, nb2 = v.z / Hf, nb3 = v.w / Hf;
        snb[n] = make_float4(nb0, nb1, nb2, nb3);
        slab[n] = lab;
        if (s > THRES) {
            float cx = (nb0 + nb2) * 0.5f;
            float cy = (nb1 + nb3) * 0.5f;
            int px = 0, py = 0;
#pragma unroll
            for (int j = 1; j < RES; ++j) {
                float bj = (float)j / (float)RES;   // bins = arange(1,7)/7 in fp32
                px += (cx >= ar * bj) ? 1 : 0;      // digitize, right=False
                py += (cy >= bj) ? 1 : 0;
            }
            int bin = py * RES + px;
            unsigned long long cur =
                ((unsigned long long)(unsigned int)__float_as_int(s) << 32)
                | (unsigned long long)(0xFFFFFFFFu - (unsigned int)n);
            unsigned long long* sl = &slots[bin * MAXDETS];
#pragma unroll
            for (int k = 0; k < MAXDETS; ++k) {
                unsigned long long old = atomicMax(&sl[k], cur);
                cur = (old < cur) ? old : cur;  // loser cascades to next slot
                if (cur == 0ULL) break;
            }
        }
    }
    __syncthreads();

    // ---- Phase 2: 147 threads emit (cell, k); LDS-only reads ----
    if (tid < NSLOT) {
        const int k = tid / NCELL;      // det slot 0..2
        const int cell = tid % NCELL;   // 0..48
        unsigned long long key = slots[cell * MAXDETS + k];
        float f0 = -1.0f, f1 = -1.0f, f2 = -1.0f, f3 = -1.0f, f4 = -1.0f;
        int cls = 0;
        if (key != 0ULL) {
            float s = __int_as_float((int)(key >> 32));
            int idx = (int)(0xFFFFFFFFu - (unsigned int)(key & 0xFFFFFFFFULL));
            float4 v = snb[idx];
            f0 = s;
            f1 = (v.z - v.x) / ar;
            f2 = v.w - v.y;
            f3 = v.x / ar;
            f4 = v.y;
            cls = slab[idx];
        }
        // classes_out[b, k, cell] — threads 0..146 write contiguously
        out[(size_t)b * NSLOT + k * NCELL + cell] = (float)cls;
        // boxes_out[b, k*5 + f, cell]
        float* ob = out + (size_t)B * NSLOT
                        + (size_t)b * (MAXDETS * 5 * NCELL)
                        + (k * 5) * NCELL + cell;
        ob[0 * NCELL] = f0;
        ob[1 * NCELL] = f1;
        ob[2 * NCELL] = f2;
        ob[3 * NCELL] = f3;
        ob[4 * NCELL] = f4;
    }
}

extern "C" void kernel_launch(void* const* d_in, const int* in_sizes, int n_in,
                              void* d_out, int out_size, void* d_ws, size_t ws_size,
                              hipStream_t stream) {
    const float* boxes  = (const float*)d_in[0];
    const int*   labels = (const int*)d_in[1];
    const float* scores = (const float*)d_in[2];
    const int*   Hp     = (const int*)d_in[3];
    const int*   Wp     = (const int*)d_in[4];
    float* out = (float*)d_out;

    int B = out_size / (NCELL * (MAXDETS + MAXDETS * 5));  // 882 per batch
    int N = in_sizes[2] / B;   // pred_scores is [B,N]

    size_t shmem = (size_t)N * (sizeof(float4) + sizeof(int));  // 20 B/box
    frcnn_post<<<B, 1024, shmem, stream>>>(boxes, labels, scores, Hp, Wp, out, B, N);
}